// Round 11
// baseline (2443.104 us; speedup 1.0000x reference)
//
#include <hip/hip_runtime.h>
#include <hip/hip_bf16.h>

#define T_ 256
#define B_ 64
#define NWG 32      // recurrence WGs: each owns 16 h-dims; 4 waves = 4 independent barrier groups

typedef __attribute__((ext_vector_type(8))) short bf16x8;
typedef __attribute__((ext_vector_type(4))) float f32x4;

__device__ __forceinline__ float bf2f(unsigned short u){
  unsigned int i = ((unsigned int)u) << 16;
  float f; __builtin_memcpy(&f, &i, 4); return f;
}
__device__ __forceinline__ unsigned short f2bf(float f){
  __hip_bfloat16 h = __float2bfloat16(f);
  unsigned short u; __builtin_memcpy(&u, &h, 2); return u;
}
// fast transcendentals: rel err ~1e-6, negligible vs bf16 state rounding (4e-3)
__device__ __forceinline__ float fsigm(float x){ return 1.0f/(1.0f + __expf(-x)); }
__device__ __forceinline__ float ftanh(float x){ return 1.0f - 2.0f/(__expf(2.0f*x) + 1.0f); }

// agent-scope (sc-flagged) accessors, RELAXED only (r8 lesson: acq/rel emit
// L2-wide maintenance). These execute at the device coherence point.
__device__ __forceinline__ bf16x8 ld_h8(const unsigned short* p){
  union { unsigned long long q[2]; bf16x8 v; } u;
  u.q[0] = __hip_atomic_load((const unsigned long long*)p,       __ATOMIC_RELAXED, __HIP_MEMORY_SCOPE_AGENT);
  u.q[1] = __hip_atomic_load((const unsigned long long*)(p + 4), __ATOMIC_RELAXED, __HIP_MEMORY_SCOPE_AGENT);
  return u.v;
}
__device__ __forceinline__ void st_h4(unsigned short* p, unsigned long long v){
  __hip_atomic_store((unsigned long long*)p, v, __ATOMIC_RELAXED, __HIP_MEMORY_SCOPE_AGENT);
}
__device__ __forceinline__ unsigned long long ld_h4(const unsigned short* p){
  return __hip_atomic_load((const unsigned long long*)p, __ATOMIC_RELAXED, __HIP_MEMORY_SCOPE_AGENT);
}

// ---------------- prep ----------------
__global__ void k_prep(const int* __restrict__ in0, const int* __restrict__ in1,
                       const int* __restrict__ mtok,
                       const float* __restrict__ emb0, const float* __restrict__ emb1,
                       const float* __restrict__ Wih_low, const float* __restrict__ Whh_low_f,
                       const float* __restrict__ Wih_high_f, const float* __restrict__ Whh_high_f,
                       const float* __restrict__ Wdec0_f, const float* __restrict__ Wdec1_f,
                       unsigned short* __restrict__ W0, unsigned short* __restrict__ Wlh,
                       unsigned short* __restrict__ Whhl, unsigned short* __restrict__ Wihh,
                       unsigned short* __restrict__ Whhh, unsigned short* __restrict__ Wd0,
                       unsigned short* __restrict__ Wd1, unsigned short* __restrict__ E,
                       float* __restrict__ mask, unsigned* __restrict__ stepflag,
                       unsigned* __restrict__ bar)
{
  int gid = blockIdx.x*blockDim.x + threadIdx.x;
  int gsz = gridDim.x*blockDim.x;
  for (int i=gid; i<2048*512; i+=gsz){
    int r = i>>9, c = i&511;
    W0[i]   = f2bf(Wih_low[(size_t)r*1024 + c]);
    Wlh[i]  = f2bf(Wih_low[(size_t)r*1024 + 512 + c]);
    Whhl[i] = f2bf(Whh_low_f[i]);
    Wihh[i] = f2bf(Wih_high_f[i]);
    Whhh[i] = f2bf(Whh_high_f[i]);
    Wd0[i]  = f2bf(Wdec0_f[i]);
  }
  for (int i=gid; i<512*512; i+=gsz) Wd1[i] = f2bf(Wdec1_f[i]);
  int mt = mtok[0];
  for (int i=gid; i<T_*B_*512; i+=gsz){
    int m = i>>9, k = i&511;
    int t = m>>6, b = m&63;
    float v;
    if (k < 256) v = emb0[(size_t)in0[b*T_+t]*256 + k];
    else         v = emb1[(size_t)in1[b*T_+t]*256 + (k-256)];
    E[i] = f2bf(v);
  }
  for (int i=gid; i<T_*B_; i+=gsz){
    int t = i>>6, b = i&63;
    mask[i] = (in0[b*T_+t] == mt) ? 1.0f : 0.0f;
  }
  for (int i=gid; i<T_; i+=gsz){
    unsigned f = 0;
    for (int b=0;b<B_;b++) f |= (in0[b*T_+i] == mt) ? 1u : 0u;
    stepflag[i] = f;
  }
  for (int i=gid; i<1024; i+=gsz) bar[i] = 0;   // flags[(w*32+j)*8], w<4, j<32
}

// ---------------- bf16 MFMA GEMM: out[M,N] = A[M,512] @ W[N,512]^T + bias ----------------
__launch_bounds__(256)
__global__ void k_gemm(const unsigned short* __restrict__ A,
                       const unsigned short* __restrict__ W,
                       const float* __restrict__ bias1, const float* __restrict__ bias2,
                       unsigned short* __restrict__ out16, float* __restrict__ out32,
                       int N, int mode)
{
  __shared__ unsigned short As[128*40];
  __shared__ unsigned short Bs[128*40];
  const int tid = threadIdx.x;
  const int m0 = blockIdx.x*128, n0 = blockIdx.y*128;
  const int wid = tid>>6, lane = tid&63;
  const int wm = (wid>>1)*64, wn = (wid&1)*64;
  const int lr = lane&15, lk = lane>>4;
  f32x4 acc[4][4] = {};
  for (int k0=0; k0<512; k0+=32){
    __syncthreads();
    #pragma unroll
    for (int i=0;i<2;i++){
      int eb = tid + 256*i;
      int row = eb>>2, kb = eb&3;
      *(bf16x8*)&As[row*40 + kb*8] = *(const bf16x8*)&A[(size_t)(m0+row)*512 + k0 + kb*8];
      *(bf16x8*)&Bs[row*40 + kb*8] = *(const bf16x8*)&W[(size_t)(n0+row)*512 + k0 + kb*8];
    }
    __syncthreads();
    bf16x8 af[4], bff[4];
    #pragma unroll
    for (int i=0;i<4;i++){
      af[i]  = *(const bf16x8*)&As[(wm + i*16 + lr)*40 + lk*8];
      bff[i] = *(const bf16x8*)&Bs[(wn + i*16 + lr)*40 + lk*8];
    }
    #pragma unroll
    for (int mi=0;mi<4;mi++)
      #pragma unroll
      for (int ni=0;ni<4;ni++)
        acc[mi][ni] = __builtin_amdgcn_mfma_f32_16x16x32_bf16(af[mi], bff[ni], acc[mi][ni], 0,0,0);
  }
  #pragma unroll
  for (int mi=0;mi<4;mi++){
    #pragma unroll
    for (int ni=0;ni<4;ni++){
      int n = n0 + wn + ni*16 + lr;
      float bb = bias1 ? bias1[n] : 0.0f;
      if (bias2) bb += bias2[n];
      #pragma unroll
      for (int r=0;r<4;r++){
        int m = m0 + wm + mi*16 + lk*4 + r;
        float v = acc[mi][ni][r] + bb;
        if (mode == 0){
          out16[(size_t)m*N + n] = f2bf(v);
        } else {
          int t = m>>6, b = m&63;
          out32[((size_t)b*T_ + t)*N + n] = v;
        }
      }
    }
  }
}

// -------- per-WAVE barrier: 4 independent groups of 32 waves (wave w of each WG) --------
// Waves are data-independent after init (gb/hht/cl/ch are wave-partitioned by batch),
// so no intra-WG __syncthreads in the main loop. Arrive: per-wave vmcnt(0) drain
// (own h-stores at coherence point) + fire-and-forget own flag. Wait: all 64 lanes
// poll the group's 32 flags in parallel + ballot.
__device__ __forceinline__ void w_arrive(unsigned* flags, int w, int j, unsigned gen){
  asm volatile("s_waitcnt vmcnt(0)" ::: "memory");   // this wave's stores visible
  if ((threadIdx.x & 63) == 0)
    __hip_atomic_store(&flags[(w*NWG + j)*8], gen+1u, __ATOMIC_RELAXED, __HIP_MEMORY_SCOPE_AGENT);
  __builtin_amdgcn_sched_barrier(0);
}
__device__ __forceinline__ void w_wait(const unsigned* flags, int w, unsigned gen){
  const unsigned* fp = &flags[(w*NWG + (threadIdx.x & (NWG-1)))*8];
  for(;;){
    unsigned v = __hip_atomic_load(fp, __ATOMIC_RELAXED, __HIP_MEMORY_SCOPE_AGENT);
    if (__ballot(v >= gen+1u) == ~0ull) break;
    __builtin_amdgcn_s_sleep(1);
  }
  __builtin_amdgcn_sched_barrier(0);
}

// hht[b][n] = Wlh_rows(n) . h_h[b,:]  (wave-local cache, recomputed on flagged steps)
__device__ __forceinline__ void compute_hht(const unsigned short* __restrict__ hh,
                                            const unsigned short* __restrict__ Wlh,
                                            float* hht, int d0, int mb, int lr, int lk)
{
  bf16x8 av[16];
  #pragma unroll
  for (int ks=0;ks<16;ks++)
    av[ks] = ld_h8(&hh[(mb+lr)*512 + ks*32 + lk*8]);
  f32x4 a[4] = {};
  #pragma unroll
  for (int ks=0;ks<16;ks++){
    #pragma unroll
    for (int g=0; g<4; g++){
      bf16x8 bg = *(const bf16x8*)&Wlh[(size_t)(g*512 + d0 + lr)*512 + ks*32 + lk*8];
      a[g] = __builtin_amdgcn_mfma_f32_16x16x32_bf16(av[ks], bg, a[g], 0,0,0);
    }
  }
  #pragma unroll
  for (int g=0; g<4; g++)
    #pragma unroll
    for (int r=0;r<4;r++){
      int b = mb + lk*4 + r;
      hht[b*68 + g*16 + lr] = a[g][r];
    }
}

// ---------------- persistent recurrence: 32 WGs, WG j owns h-dims [16j, 16j+16) ----------------
__launch_bounds__(256)
__global__ void k_recur(const float* __restrict__ h_low0, const float* __restrict__ c_low0,
                        const float* __restrict__ h_high0, const float* __restrict__ c_high0,
                        const float* __restrict__ bih_high, const float* __restrict__ bhh_high,
                        const unsigned short* __restrict__ xW,
                        const unsigned short* __restrict__ Whhl,
                        const unsigned short* __restrict__ Wlh,
                        const unsigned short* __restrict__ Wihh,
                        const unsigned short* __restrict__ Whhh,
                        const float* __restrict__ mask, const unsigned* __restrict__ stepflag,
                        unsigned short* __restrict__ hl_buf, unsigned short* __restrict__ hh_buf,
                        unsigned short* __restrict__ hseq, unsigned* bar,
                        float* __restrict__ outS)
{
  __shared__ unsigned short Ws[64*520];   // Whh_low slice (64 gate rows), LDS-resident
  __shared__ float hht[64*68];
  __shared__ float gb[64*68];
  __shared__ float cl[64*16];
  __shared__ float ch[64*16];
  const int tid = threadIdx.x;
  const int j = blockIdx.x;
  const int d0 = j*16;
  const int wid = tid>>6, lane = tid&63;
  const int lr = lane&15, lk = lane>>4;
  const int mb = wid*16;          // this wave's 16 batches — also its barrier group
  const int eb = tid>>2;          // elementwise batch (within wave's group: eb in [mb,mb+16))
  const int ep = (tid&3)*4;       // 4 dims per thread

  for (int i=tid; i<64*64; i+=256){
    int n = i>>6, cb = i&63;
    int grow = (n>>4)*512 + d0 + (n&15);
    *(bf16x8*)&Ws[n*520 + cb*8] = *(const bf16x8*)&Whhl[(size_t)grow*512 + cb*8];
  }
  for (int i=tid; i<1024; i+=256){
    int b=i>>4, dd=i&15;
    cl[i] = c_low0[b*512 + d0 + dd];
    ch[i] = c_high0[b*512 + d0 + dd];
  }
  {
    int gi = eb*512 + d0 + ep;
    unsigned long long l0 = (unsigned long long)f2bf(h_low0[gi])        | ((unsigned long long)f2bf(h_low0[gi+1])<<16)
                          | ((unsigned long long)f2bf(h_low0[gi+2])<<32)| ((unsigned long long)f2bf(h_low0[gi+3])<<48);
    unsigned long long h0 = (unsigned long long)f2bf(h_high0[gi])        | ((unsigned long long)f2bf(h_high0[gi+1])<<16)
                          | ((unsigned long long)f2bf(h_high0[gi+2])<<32)| ((unsigned long long)f2bf(h_high0[gi+3])<<48);
    st_h4(&hl_buf[gi], l0);
    st_h4(&hh_buf[gi], h0);
  }
  __syncthreads();                 // publish LDS init (Ws, cl, ch) across waves — ONLY sync in kernel
  unsigned gen = 0;
  w_arrive(bar, wid, j, gen);
  w_wait(bar, wid, gen); gen++;
  // prefetch xW(t=0): consumed at t=0 elementwise; hides under compute_hht
  unsigned long long cxi, cxf, cxg, cxo, nxi, nxf, nxg, nxo;
  {
    size_t xr = (size_t)eb*2048 + d0 + ep;
    cxi = *(const unsigned long long*)&xW[xr];
    cxf = *(const unsigned long long*)&xW[xr + 512];
    cxg = *(const unsigned long long*)&xW[xr + 1024];
    cxo = *(const unsigned long long*)&xW[xr + 1536];
  }
  compute_hht(hh_buf, Wlh, hht, d0, mb, lr, lk);

  int hs = 0;
  for (int t=0; t<T_; t++){
    const int rl = t&1, wl = rl^1;
    const unsigned short* hlr = hl_buf + rl*32768;
    // ---- phase A: low cell ----
    bf16x8 av[16];
    #pragma unroll
    for (int ks=0;ks<16;ks++)
      av[ks] = ld_h8(&hlr[(mb+lr)*512 + ks*32 + lk*8]);
    // prefetch NEXT step's xW: issued now, consumed at t+1 — never on the sync chain
    if (t+1 < T_){
      size_t xr = ((size_t)(t+1)*64 + eb)*2048 + d0 + ep;
      nxi = *(const unsigned long long*)&xW[xr];
      nxf = *(const unsigned long long*)&xW[xr + 512];
      nxg = *(const unsigned long long*)&xW[xr + 1024];
      nxo = *(const unsigned long long*)&xW[xr + 1536];
    }
    f32x4 a[4] = {};
    #pragma unroll
    for (int ks=0;ks<16;ks++){
      #pragma unroll
      for (int g=0; g<4; g++){
        bf16x8 bg = *(const bf16x8*)&Ws[(g*16+lr)*520 + ks*32 + lk*8];
        a[g] = __builtin_amdgcn_mfma_f32_16x16x32_bf16(av[ks], bg, a[g], 0,0,0);
      }
    }
    #pragma unroll
    for (int g=0; g<4; g++)
      #pragma unroll
      for (int r=0;r<4;r++){
        int b = mb + lk*4 + r;
        gb[b*68 + g*16 + lr] = a[g][r] + hht[b*68 + g*16 + lr];
      }
    // elementwise: gb rows are wave-local (eb in [mb,mb+16)); wave-lockstep makes
    // ds_write -> ds_read safe with lgkmcnt only (no barrier needed)
    unsigned long long hp;
    {
      const int b = eb;
      unsigned short hb[4];
      #pragma unroll
      for (int q=0;q<4;q++){
        int dd = ep + q;
        float g_i = gb[b*68 + dd]      + bf2f((unsigned short)(cxi >> (16*q)));
        float g_f = gb[b*68 + 16 + dd] + bf2f((unsigned short)(cxf >> (16*q)));
        float g_g = gb[b*68 + 32 + dd] + bf2f((unsigned short)(cxg >> (16*q)));
        float g_o = gb[b*68 + 48 + dd] + bf2f((unsigned short)(cxo >> (16*q)));
        float c = fsigm(g_f)*cl[b*16+dd] + fsigm(g_i)*ftanh(g_g);
        float h = fsigm(g_o)*ftanh(c);
        cl[b*16+dd] = c;
        hb[q] = f2bf(h);
      }
      hp = (unsigned long long)hb[0] | ((unsigned long long)hb[1]<<16)
         | ((unsigned long long)hb[2]<<32) | ((unsigned long long)hb[3]<<48);
      st_h4(&hl_buf[wl*32768 + b*512 + d0 + ep], hp);
      *(unsigned long long*)&hseq[((size_t)t*64 + b)*512 + d0 + ep] = hp;  // parallel transaction
    }
    w_arrive(bar, wid, j, gen);
    w_wait(bar, wid, gen); gen++;
    cxi = nxi; cxf = nxf; cxg = nxg; cxo = nxo;
    // ---- phase B: high cell (only ~8/256 steps) ----
    if (stepflag[t]){
      const unsigned short* hln = hl_buf + wl*32768;
      const unsigned short* hhr = hh_buf + hs*32768;
      bf16x8 avl[16], avh[16];
      #pragma unroll
      for (int ks=0;ks<16;ks++){
        avl[ks] = ld_h8(&hln[(mb+lr)*512 + ks*32 + lk*8]);
        avh[ks] = ld_h8(&hhr[(mb+lr)*512 + ks*32 + lk*8]);
      }
      f32x4 hacc[4] = {};
      #pragma unroll
      for (int ks=0;ks<16;ks++){
        #pragma unroll
        for (int g=0; g<4; g++){
          size_t grw = (size_t)(g*512 + d0 + lr)*512 + ks*32 + lk*8;
          bf16x8 bi = *(const bf16x8*)&Wihh[grw];
          bf16x8 bh = *(const bf16x8*)&Whhh[grw];
          hacc[g] = __builtin_amdgcn_mfma_f32_16x16x32_bf16(avl[ks], bi, hacc[g], 0,0,0);
          hacc[g] = __builtin_amdgcn_mfma_f32_16x16x32_bf16(avh[ks], bh, hacc[g], 0,0,0);
        }
      }
      #pragma unroll
      for (int g=0; g<4; g++)
        #pragma unroll
        for (int r=0;r<4;r++){
          int b = mb + lk*4 + r;
          gb[b*68 + g*16 + lr] = hacc[g][r];
        }
      {
        const int b = eb;
        float m = mask[t*64 + b];
        unsigned long long hold4 = ld_h4(&hh_buf[hs*32768 + b*512 + d0 + ep]);
        unsigned short hn[4];
        #pragma unroll
        for (int q=0;q<4;q++){
          int dd = ep + q; int d = d0 + dd;
          float g_i = gb[b*68+dd]      + bih_high[d]      + bhh_high[d];
          float g_f = gb[b*68+16+dd]   + bih_high[512+d]  + bhh_high[512+d];
          float g_g = gb[b*68+32+dd]   + bih_high[1024+d] + bhh_high[1024+d];
          float g_o = gb[b*68+48+dd]   + bih_high[1536+d] + bhh_high[1536+d];
          float ct = fsigm(g_f)*ch[b*16+dd] + fsigm(g_i)*ftanh(g_g);
          float ht = fsigm(g_o)*ftanh(ct);
          float hold = bf2f((unsigned short)(hold4 >> (16*q)));
          hn[q] = f2bf(m*ht + (1.0f-m)*hold);
          ch[b*16+dd] = m*ct + (1.0f-m)*ch[b*16+dd];
        }
        unsigned long long hq = (unsigned long long)hn[0] | ((unsigned long long)hn[1]<<16)
                              | ((unsigned long long)hn[2]<<32) | ((unsigned long long)hn[3]<<48);
        st_h4(&hh_buf[(hs^1)*32768 + eb*512 + d0 + ep], hq);
      }
      w_arrive(bar, wid, j, gen);
      w_wait(bar, wid, gen); gen++;
      hs ^= 1;
      compute_hht(hh_buf + hs*32768, Wlh, hht, d0, mb, lr, lk);
    }
  }
  // final states -> f32 (h_l in slot 0 after t=255); all wave-local reads
  {
    int gi = eb*512 + d0 + ep;
    unsigned long long hl4 = ld_h4(&hl_buf[gi]);
    unsigned long long hh4 = ld_h4(&hh_buf[hs*32768 + gi]);
    #pragma unroll
    for (int q=0;q<4;q++){
      outS[gi+q]           = bf2f((unsigned short)(hl4 >> (16*q)));
      outS[32768 + gi + q] = cl[eb*16 + ep + q];
      outS[65536 + gi + q] = bf2f((unsigned short)(hh4 >> (16*q)));
      outS[98304 + gi + q] = ch[eb*16 + ep + q];
    }
  }
}

extern "C" void kernel_launch(void* const* d_in, const int* in_sizes, int n_in,
                              void* d_out, int out_size, void* d_ws, size_t ws_size,
                              hipStream_t stream)
{
  const int*   in0    = (const int*)  d_in[0];
  const int*   in1    = (const int*)  d_in[1];
  const float* hl0    = (const float*)d_in[2];
  const float* cl0    = (const float*)d_in[3];
  const float* hh0    = (const float*)d_in[4];
  const float* ch0    = (const float*)d_in[5];
  const int*   mtok   = (const int*)  d_in[6];
  const float* emb0   = (const float*)d_in[7];
  const float* emb1   = (const float*)d_in[8];
  const float* Wihl_f = (const float*)d_in[9];
  const float* bihl   = (const float*)d_in[10];
  const float* Whhl_f = (const float*)d_in[11];
  const float* bhhl   = (const float*)d_in[12];
  const float* Wihh_f = (const float*)d_in[13];
  const float* bihh   = (const float*)d_in[14];
  const float* Whhh_f = (const float*)d_in[15];
  const float* bhhh   = (const float*)d_in[16];
  const float* Wd0_f  = (const float*)d_in[17];
  const float* bd0    = (const float*)d_in[18];
  const float* Wd1_f  = (const float*)d_in[19];
  const float* bd1    = (const float*)d_in[20];

  // d_out is FLOAT: dec0 [B,T,2048] @0, dec1 [B,T,512] @33554432, states @41943040.
  float* dout = (float*)d_out;
  unsigned short* xW = (unsigned short*)dout;              // 64 MiB scratch in dec0 region
  unsigned short* E  = (unsigned short*)(dout + 33554432); // 16 MiB scratch in dec1 region

  char* ws = (char*)d_ws;
  unsigned short* hseq = (unsigned short*)(ws + 0);          // [16384][512] bf16, 16 MiB
  unsigned short* W0   = (unsigned short*)(ws + 16777216);
  unsigned short* Wlh  = (unsigned short*)(ws + 18874368);
  unsigned short* Whhl = (unsigned short*)(ws + 20971520);
  unsigned short* Wihh = (unsigned short*)(ws + 23068672);
  unsigned short* Whhh = (unsigned short*)(ws + 25165824);
  unsigned short* Wd0  = (unsigned short*)(ws + 27262976);
  unsigned short* Wd1  = (unsigned short*)(ws + 29360128);
  unsigned short* hlb  = (unsigned short*)(ws + 29884416);   // [2][64][512] bf16
  unsigned short* hhb  = (unsigned short*)(ws + 30015488);   // [2][64][512] bf16
  float*          mask = (float*)    (ws + 30146560);        // [256][64]
  unsigned*       sflg = (unsigned*) (ws + 30212096);        // [256]
  unsigned*       bar  = (unsigned*) (ws + 30213120);        // flags[4*32*8] u32

  k_prep<<<2048, 256, 0, stream>>>(in0,in1,mtok,emb0,emb1,Wihl_f,Whhl_f,Wihh_f,Whhh_f,Wd0_f,Wd1_f,
                                   W0,Wlh,Whhl,Wihh,Whhh,Wd0,Wd1,E,mask,sflg,bar);
  dim3 g1(128,16);
  k_gemm<<<g1, 256, 0, stream>>>(E, W0, bihl, bhhl, xW, nullptr, 2048, 0);
  k_recur<<<NWG, 256, 0, stream>>>(hl0,cl0,hh0,ch0,bihh,bhhh,xW,Whhl,Wlh,Wihh,Whhh,
                                   mask,sflg,hlb,hhb,hseq,bar,dout + 41943040);
  k_gemm<<<g1, 256, 0, stream>>>(hseq, Wd0, bd0, nullptr, nullptr, dout, 2048, 1);
  dim3 g2(128,4);
  k_gemm<<<g2, 256, 0, stream>>>(hseq, Wd1, bd1, nullptr, nullptr, dout + 33554432, 512, 1);
}

// Round 12
// 1941.434 us; speedup vs baseline: 1.2584x; 1.2584x over previous
//
#include <hip/hip_runtime.h>
#include <hip/hip_bf16.h>

#define T_ 256
#define B_ 64
#define NWG 32      // recurrence WGs: each owns 16 h-dims

typedef __attribute__((ext_vector_type(8))) short bf16x8;
typedef __attribute__((ext_vector_type(4))) float f32x4;
typedef __attribute__((ext_vector_type(4))) unsigned uint4v;
union v128 { uint4v u4; bf16x8 h8; };

__device__ __forceinline__ float bf2f(unsigned short u){
  unsigned int i = ((unsigned int)u) << 16;
  float f; __builtin_memcpy(&f, &i, 4); return f;
}
__device__ __forceinline__ unsigned short f2bf(float f){
  __hip_bfloat16 h = __float2bfloat16(f);
  unsigned short u; __builtin_memcpy(&u, &h, 2); return u;
}
// fast transcendentals: rel err ~1e-6, negligible vs bf16 state rounding
__device__ __forceinline__ float fsigm(float x){ return 1.0f/(1.0f + __expf(-x)); }
__device__ __forceinline__ float ftanh(float x){ return 1.0f - 2.0f/(__expf(2.0f*x) + 1.0f); }

// ---- coherent-point PLAIN accessors: sc0 sc1 = bypass L1+L2, served at MALL
// (same coherence point the agent-scope atomics use) but fully pipelined —
// no per-op atomic serialization. Caller drains with one vmcnt(0).
__device__ __forceinline__ void ld16_cc_issue(v128* dst, const unsigned short* p){
  asm volatile("global_load_dwordx4 %0, %1, off sc0 sc1" : "=v"(dst->u4) : "v"(p) : "memory");
}
__device__ __forceinline__ void st8_cc(unsigned short* p, unsigned long long v){
  asm volatile("global_store_dwordx2 %0, %1, off sc0 sc1" :: "v"(p), "v"(v) : "memory");
}
__device__ __forceinline__ unsigned long long ld8_cc(const unsigned short* p){
  unsigned long long v;
  asm volatile("global_load_dwordx2 %0, %1, off sc0 sc1\n\ts_waitcnt vmcnt(0)"
               : "=v"(v) : "v"(p) : "memory");
  return v;
}

// ---------------- prep ----------------
__global__ void k_prep(const int* __restrict__ in0, const int* __restrict__ in1,
                       const int* __restrict__ mtok,
                       const float* __restrict__ emb0, const float* __restrict__ emb1,
                       const float* __restrict__ Wih_low, const float* __restrict__ Whh_low_f,
                       const float* __restrict__ Wih_high_f, const float* __restrict__ Whh_high_f,
                       const float* __restrict__ Wdec0_f, const float* __restrict__ Wdec1_f,
                       unsigned short* __restrict__ W0, unsigned short* __restrict__ Wlh,
                       unsigned short* __restrict__ Whhl, unsigned short* __restrict__ Wihh,
                       unsigned short* __restrict__ Whhh, unsigned short* __restrict__ Wd0,
                       unsigned short* __restrict__ Wd1, unsigned short* __restrict__ E,
                       float* __restrict__ mask, unsigned* __restrict__ stepflag,
                       unsigned* __restrict__ bar)
{
  int gid = blockIdx.x*blockDim.x + threadIdx.x;
  int gsz = gridDim.x*blockDim.x;
  for (int i=gid; i<2048*512; i+=gsz){
    int r = i>>9, c = i&511;
    W0[i]   = f2bf(Wih_low[(size_t)r*1024 + c]);
    Wlh[i]  = f2bf(Wih_low[(size_t)r*1024 + 512 + c]);
    Whhl[i] = f2bf(Whh_low_f[i]);
    Wihh[i] = f2bf(Wih_high_f[i]);
    Whhh[i] = f2bf(Whh_high_f[i]);
    Wd0[i]  = f2bf(Wdec0_f[i]);
  }
  for (int i=gid; i<512*512; i+=gsz) Wd1[i] = f2bf(Wdec1_f[i]);
  int mt = mtok[0];
  for (int i=gid; i<T_*B_*512; i+=gsz){
    int m = i>>9, k = i&511;
    int t = m>>6, b = m&63;
    float v;
    if (k < 256) v = emb0[(size_t)in0[b*T_+t]*256 + k];
    else         v = emb1[(size_t)in1[b*T_+t]*256 + (k-256)];
    E[i] = f2bf(v);
  }
  for (int i=gid; i<T_*B_; i+=gsz){
    int t = i>>6, b = i&63;
    mask[i] = (in0[b*T_+t] == mt) ? 1.0f : 0.0f;
  }
  for (int i=gid; i<T_; i+=gsz){
    unsigned f = 0;
    for (int b=0;b<B_;b++) f |= (in0[b*T_+i] == mt) ? 1u : 0u;
    stepflag[i] = f;
  }
  for (int i=gid; i<1024; i+=gsz) bar[i] = 0;   // flags[j*32], j<32
}

// ---------------- bf16 MFMA GEMM: out[M,N] = A[M,512] @ W[N,512]^T + bias ----------------
__launch_bounds__(256)
__global__ void k_gemm(const unsigned short* __restrict__ A,
                       const unsigned short* __restrict__ W,
                       const float* __restrict__ bias1, const float* __restrict__ bias2,
                       unsigned short* __restrict__ out16, float* __restrict__ out32,
                       int N, int mode)
{
  __shared__ unsigned short As[128*40];
  __shared__ unsigned short Bs[128*40];
  const int tid = threadIdx.x;
  const int m0 = blockIdx.x*128, n0 = blockIdx.y*128;
  const int wid = tid>>6, lane = tid&63;
  const int wm = (wid>>1)*64, wn = (wid&1)*64;
  const int lr = lane&15, lk = lane>>4;
  f32x4 acc[4][4] = {};
  for (int k0=0; k0<512; k0+=32){
    __syncthreads();
    #pragma unroll
    for (int i=0;i<2;i++){
      int eb = tid + 256*i;
      int row = eb>>2, kb = eb&3;
      *(bf16x8*)&As[row*40 + kb*8] = *(const bf16x8*)&A[(size_t)(m0+row)*512 + k0 + kb*8];
      *(bf16x8*)&Bs[row*40 + kb*8] = *(const bf16x8*)&W[(size_t)(n0+row)*512 + k0 + kb*8];
    }
    __syncthreads();
    bf16x8 af[4], bff[4];
    #pragma unroll
    for (int i=0;i<4;i++){
      af[i]  = *(const bf16x8*)&As[(wm + i*16 + lr)*40 + lk*8];
      bff[i] = *(const bf16x8*)&Bs[(wn + i*16 + lr)*40 + lk*8];
    }
    #pragma unroll
    for (int mi=0;mi<4;mi++)
      #pragma unroll
      for (int ni=0;ni<4;ni++)
        acc[mi][ni] = __builtin_amdgcn_mfma_f32_16x16x32_bf16(af[mi], bff[ni], acc[mi][ni], 0,0,0);
  }
  #pragma unroll
  for (int mi=0;mi<4;mi++){
    #pragma unroll
    for (int ni=0;ni<4;ni++){
      int n = n0 + wn + ni*16 + lr;
      float bb = bias1 ? bias1[n] : 0.0f;
      if (bias2) bb += bias2[n];
      #pragma unroll
      for (int r=0;r<4;r++){
        int m = m0 + wm + mi*16 + lk*4 + r;
        float v = acc[mi][ni][r] + bb;
        if (mode == 0){
          out16[(size_t)m*N + n] = f2bf(v);
        } else {
          int t = m>>6, b = m&63;
          out32[((size_t)b*T_ + t)*N + n] = v;
        }
      }
    }
  }
}

// ------- all-flags barrier (r9-verified): atomic flags, WG-level -------
__device__ __forceinline__ void g_arrive(unsigned* flags, int j, unsigned gen){
  asm volatile("s_waitcnt vmcnt(0)" ::: "memory");   // drain this wave's sc0sc1 h-stores
  __syncthreads();                                    // all waves drained
  if (threadIdx.x == 0)
    __hip_atomic_store(&flags[j*32], gen+1u, __ATOMIC_RELAXED, __HIP_MEMORY_SCOPE_AGENT);
  __builtin_amdgcn_sched_barrier(0);
}
__device__ __forceinline__ void g_wait(const unsigned* flags, unsigned gen){
  if (threadIdx.x < 64){
    const unsigned* fp = &flags[(threadIdx.x & (NWG-1))*32];
    for(;;){
      unsigned v = __hip_atomic_load(fp, __ATOMIC_RELAXED, __HIP_MEMORY_SCOPE_AGENT);
      if (__ballot(v >= gen+1u) == ~0ull) break;
      __builtin_amdgcn_s_sleep(1);
    }
  }
  __builtin_amdgcn_sched_barrier(0);
  __syncthreads();
  __builtin_amdgcn_sched_barrier(0);
}

// hht[b][n] = Wlh_rows(n) . h_h[b,:]  (cached, recomputed only on flagged steps)
__device__ __forceinline__ void compute_hht(const unsigned short* __restrict__ hh,
                                            const unsigned short* __restrict__ Wlh,
                                            float* hht, int d0, int mb, int lr, int lk)
{
  v128 av[16];
  #pragma unroll
  for (int ks=0;ks<16;ks++)
    ld16_cc_issue(&av[ks], hh + (mb+lr)*512 + ks*32 + lk*8);
  asm volatile("s_waitcnt vmcnt(0)" ::: "memory");
  __builtin_amdgcn_sched_barrier(0);
  f32x4 a[4] = {};
  #pragma unroll
  for (int ks=0;ks<16;ks++){
    #pragma unroll
    for (int g=0; g<4; g++){
      bf16x8 bg = *(const bf16x8*)&Wlh[(size_t)(g*512 + d0 + lr)*512 + ks*32 + lk*8];
      a[g] = __builtin_amdgcn_mfma_f32_16x16x32_bf16(av[ks].h8, bg, a[g], 0,0,0);
    }
  }
  #pragma unroll
  for (int g=0; g<4; g++)
    #pragma unroll
    for (int r=0;r<4;r++){
      int b = mb + lk*4 + r;
      hht[b*68 + g*16 + lr] = a[g][r];
    }
}

// ---------------- persistent recurrence: 32 WGs, WG j owns h-dims [16j, 16j+16) ----------------
__launch_bounds__(256)
__global__ void k_recur(const float* __restrict__ h_low0, const float* __restrict__ c_low0,
                        const float* __restrict__ h_high0, const float* __restrict__ c_high0,
                        const float* __restrict__ bih_high, const float* __restrict__ bhh_high,
                        const unsigned short* __restrict__ xW,
                        const unsigned short* __restrict__ Whhl,
                        const unsigned short* __restrict__ Wlh,
                        const unsigned short* __restrict__ Wihh,
                        const unsigned short* __restrict__ Whhh,
                        const float* __restrict__ mask, const unsigned* __restrict__ stepflag,
                        unsigned short* __restrict__ hl_buf, unsigned short* __restrict__ hh_buf,
                        unsigned short* __restrict__ hseq, unsigned* bar,
                        float* __restrict__ outS)
{
  __shared__ unsigned short Ws[64*520];   // Whh_low slice (64 gate rows), LDS-resident
  __shared__ float hht[64*68];
  __shared__ float gb[64*68];
  __shared__ float cl[64*16];
  __shared__ float ch[64*16];
  const int tid = threadIdx.x;
  const int j = blockIdx.x;
  const int d0 = j*16;
  const int wid = tid>>6, lane = tid&63;
  const int lr = lane&15, lk = lane>>4;
  const int mb = wid*16;
  const int eb = tid>>2;          // elementwise batch (eb in [mb,mb+16) for this wave)
  const int ep = (tid&3)*4;       // 4 dims per thread

  for (int i=tid; i<64*64; i+=256){
    int n = i>>6, cb = i&63;
    int grow = (n>>4)*512 + d0 + (n&15);
    *(bf16x8*)&Ws[n*520 + cb*8] = *(const bf16x8*)&Whhl[(size_t)grow*512 + cb*8];
  }
  for (int i=tid; i<1024; i+=256){
    int b=i>>4, dd=i&15;
    cl[i] = c_low0[b*512 + d0 + dd];
    ch[i] = c_high0[b*512 + d0 + dd];
  }
  {
    int gi = eb*512 + d0 + ep;
    unsigned long long l0 = (unsigned long long)f2bf(h_low0[gi])        | ((unsigned long long)f2bf(h_low0[gi+1])<<16)
                          | ((unsigned long long)f2bf(h_low0[gi+2])<<32)| ((unsigned long long)f2bf(h_low0[gi+3])<<48);
    unsigned long long h0 = (unsigned long long)f2bf(h_high0[gi])        | ((unsigned long long)f2bf(h_high0[gi+1])<<16)
                          | ((unsigned long long)f2bf(h_high0[gi+2])<<32)| ((unsigned long long)f2bf(h_high0[gi+3])<<48);
    st8_cc(&hl_buf[gi], l0);
    st8_cc(&hh_buf[gi], h0);
  }
  unsigned gen = 0;
  g_arrive(bar, j, gen);          // also publishes LDS init via its __syncthreads
  g_wait(bar, gen); gen++;
  // prefetch xW(t=0): plain cached loads, completes under compute_hht
  unsigned long long cxi, cxf, cxg, cxo, nxi, nxf, nxg, nxo;
  {
    size_t xr = (size_t)eb*2048 + d0 + ep;
    cxi = *(const unsigned long long*)&xW[xr];
    cxf = *(const unsigned long long*)&xW[xr + 512];
    cxg = *(const unsigned long long*)&xW[xr + 1024];
    cxo = *(const unsigned long long*)&xW[xr + 1536];
  }
  compute_hht(hh_buf, Wlh, hht, d0, mb, lr, lk);
  __syncthreads();

  int hs = 0;
  for (int t=0; t<T_; t++){
    const int rl = t&1, wl = rl^1;
    const unsigned short* hlr = hl_buf + rl*32768;
    // ---- phase A: low cell ----
    v128 av[16];
    #pragma unroll
    for (int ks=0;ks<16;ks++)
      ld16_cc_issue(&av[ks], hlr + (mb+lr)*512 + ks*32 + lk*8);
    asm volatile("s_waitcnt vmcnt(0)" ::: "memory");
    __builtin_amdgcn_sched_barrier(0);
    // prefetch NEXT step's xW: issued now, consumed at t+1, completes under MFMAs
    if (t+1 < T_){
      size_t xr = ((size_t)(t+1)*64 + eb)*2048 + d0 + ep;
      nxi = *(const unsigned long long*)&xW[xr];
      nxf = *(const unsigned long long*)&xW[xr + 512];
      nxg = *(const unsigned long long*)&xW[xr + 1024];
      nxo = *(const unsigned long long*)&xW[xr + 1536];
    }
    f32x4 a[4] = {};
    #pragma unroll
    for (int ks=0;ks<16;ks++){
      #pragma unroll
      for (int g=0; g<4; g++){
        bf16x8 bg = *(const bf16x8*)&Ws[(g*16+lr)*520 + ks*32 + lk*8];
        a[g] = __builtin_amdgcn_mfma_f32_16x16x32_bf16(av[ks].h8, bg, a[g], 0,0,0);
      }
    }
    #pragma unroll
    for (int g=0; g<4; g++)
      #pragma unroll
      for (int r=0;r<4;r++){
        int b = mb + lk*4 + r;
        gb[b*68 + g*16 + lr] = a[g][r] + hht[b*68 + g*16 + lr];
      }
    // elementwise: gb/hht/cl rows are wave-local (eb in wave's range) — no barrier
    unsigned long long hp;
    {
      const int b = eb;
      unsigned short hb[4];
      #pragma unroll
      for (int q=0;q<4;q++){
        int dd = ep + q;
        float g_i = gb[b*68 + dd]      + bf2f((unsigned short)(cxi >> (16*q)));
        float g_f = gb[b*68 + 16 + dd] + bf2f((unsigned short)(cxf >> (16*q)));
        float g_g = gb[b*68 + 32 + dd] + bf2f((unsigned short)(cxg >> (16*q)));
        float g_o = gb[b*68 + 48 + dd] + bf2f((unsigned short)(cxo >> (16*q)));
        float c = fsigm(g_f)*cl[b*16+dd] + fsigm(g_i)*ftanh(g_g);
        float h = fsigm(g_o)*ftanh(c);
        cl[b*16+dd] = c;
        hb[q] = f2bf(h);
      }
      hp = (unsigned long long)hb[0] | ((unsigned long long)hb[1]<<16)
         | ((unsigned long long)hb[2]<<32) | ((unsigned long long)hb[3]<<48);
      st8_cc(&hl_buf[wl*32768 + b*512 + d0 + ep], hp);
      *(unsigned long long*)&hseq[((size_t)t*64 + b)*512 + d0 + ep] = hp;
    }
    g_arrive(bar, j, gen);
    g_wait(bar, gen); gen++;
    cxi = nxi; cxf = nxf; cxg = nxg; cxo = nxo;
    // ---- phase B: high cell (only ~8/256 steps) ----
    if (stepflag[t]){
      const unsigned short* hln = hl_buf + wl*32768;
      const unsigned short* hhr = hh_buf + hs*32768;
      v128 avl[16], avh[16];
      #pragma unroll
      for (int ks=0;ks<16;ks++){
        ld16_cc_issue(&avl[ks], hln + (mb+lr)*512 + ks*32 + lk*8);
        ld16_cc_issue(&avh[ks], hhr + (mb+lr)*512 + ks*32 + lk*8);
      }
      asm volatile("s_waitcnt vmcnt(0)" ::: "memory");
      __builtin_amdgcn_sched_barrier(0);
      f32x4 hacc[4] = {};
      #pragma unroll
      for (int ks=0;ks<16;ks++){
        #pragma unroll
        for (int g=0; g<4; g++){
          size_t grw = (size_t)(g*512 + d0 + lr)*512 + ks*32 + lk*8;
          bf16x8 bi = *(const bf16x8*)&Wihh[grw];
          bf16x8 bh = *(const bf16x8*)&Whhh[grw];
          hacc[g] = __builtin_amdgcn_mfma_f32_16x16x32_bf16(avl[ks].h8, bi, hacc[g], 0,0,0);
          hacc[g] = __builtin_amdgcn_mfma_f32_16x16x32_bf16(avh[ks].h8, bh, hacc[g], 0,0,0);
        }
      }
      #pragma unroll
      for (int g=0; g<4; g++)
        #pragma unroll
        for (int r=0;r<4;r++){
          int b = mb + lk*4 + r;
          gb[b*68 + g*16 + lr] = hacc[g][r];
        }
      {
        const int b = eb;
        float m = mask[t*64 + b];
        unsigned long long hold4 = ld8_cc(&hh_buf[hs*32768 + b*512 + d0 + ep]);
        unsigned short hn[4];
        #pragma unroll
        for (int q=0;q<4;q++){
          int dd = ep + q; int d = d0 + dd;
          float g_i = gb[b*68+dd]      + bih_high[d]      + bhh_high[d];
          float g_f = gb[b*68+16+dd]   + bih_high[512+d]  + bhh_high[512+d];
          float g_g = gb[b*68+32+dd]   + bih_high[1024+d] + bhh_high[1024+d];
          float g_o = gb[b*68+48+dd]   + bih_high[1536+d] + bhh_high[1536+d];
          float ct = fsigm(g_f)*ch[b*16+dd] + fsigm(g_i)*ftanh(g_g);
          float ht = fsigm(g_o)*ftanh(ct);
          float hold = bf2f((unsigned short)(hold4 >> (16*q)));
          hn[q] = f2bf(m*ht + (1.0f-m)*hold);
          ch[b*16+dd] = m*ct + (1.0f-m)*ch[b*16+dd];
        }
        unsigned long long hq = (unsigned long long)hn[0] | ((unsigned long long)hn[1]<<16)
                              | ((unsigned long long)hn[2]<<32) | ((unsigned long long)hn[3]<<48);
        st8_cc(&hh_buf[(hs^1)*32768 + eb*512 + d0 + ep], hq);
      }
      g_arrive(bar, j, gen);
      g_wait(bar, gen); gen++;
      hs ^= 1;
      compute_hht(hh_buf + hs*32768, Wlh, hht, d0, mb, lr, lk);
      __syncthreads();
    }
  }
  // final states -> f32 (h_l in slot 0 after t=255)
  {
    int gi = eb*512 + d0 + ep;
    unsigned long long hl4 = ld8_cc(&hl_buf[gi]);
    unsigned long long hh4 = ld8_cc(&hh_buf[hs*32768 + gi]);
    #pragma unroll
    for (int q=0;q<4;q++){
      outS[gi+q]           = bf2f((unsigned short)(hl4 >> (16*q)));
      outS[32768 + gi + q] = cl[eb*16 + ep + q];
      outS[65536 + gi + q] = bf2f((unsigned short)(hh4 >> (16*q)));
      outS[98304 + gi + q] = ch[eb*16 + ep + q];
    }
  }
}

extern "C" void kernel_launch(void* const* d_in, const int* in_sizes, int n_in,
                              void* d_out, int out_size, void* d_ws, size_t ws_size,
                              hipStream_t stream)
{
  const int*   in0    = (const int*)  d_in[0];
  const int*   in1    = (const int*)  d_in[1];
  const float* hl0    = (const float*)d_in[2];
  const float* cl0    = (const float*)d_in[3];
  const float* hh0    = (const float*)d_in[4];
  const float* ch0    = (const float*)d_in[5];
  const int*   mtok   = (const int*)  d_in[6];
  const float* emb0   = (const float*)d_in[7];
  const float* emb1   = (const float*)d_in[8];
  const float* Wihl_f = (const float*)d_in[9];
  const float* bihl   = (const float*)d_in[10];
  const float* Whhl_f = (const float*)d_in[11];
  const float* bhhl   = (const float*)d_in[12];
  const float* Wihh_f = (const float*)d_in[13];
  const float* bihh   = (const float*)d_in[14];
  const float* Whhh_f = (const float*)d_in[15];
  const float* bhhh   = (const float*)d_in[16];
  const float* Wd0_f  = (const float*)d_in[17];
  const float* bd0    = (const float*)d_in[18];
  const float* Wd1_f  = (const float*)d_in[19];
  const float* bd1    = (const float*)d_in[20];

  // d_out is FLOAT: dec0 [B,T,2048] @0, dec1 [B,T,512] @33554432, states @41943040.
  float* dout = (float*)d_out;
  unsigned short* xW = (unsigned short*)dout;              // 64 MiB scratch in dec0 region
  unsigned short* E  = (unsigned short*)(dout + 33554432); // 16 MiB scratch in dec1 region

  char* ws = (char*)d_ws;
  unsigned short* hseq = (unsigned short*)(ws + 0);          // [16384][512] bf16, 16 MiB
  unsigned short* W0   = (unsigned short*)(ws + 16777216);
  unsigned short* Wlh  = (unsigned short*)(ws + 18874368);
  unsigned short* Whhl = (unsigned short*)(ws + 20971520);
  unsigned short* Wihh = (unsigned short*)(ws + 23068672);
  unsigned short* Whhh = (unsigned short*)(ws + 25165824);
  unsigned short* Wd0  = (unsigned short*)(ws + 27262976);
  unsigned short* Wd1  = (unsigned short*)(ws + 29360128);
  unsigned short* hlb  = (unsigned short*)(ws + 29884416);   // [2][64][512] bf16
  unsigned short* hhb  = (unsigned short*)(ws + 30015488);   // [2][64][512] bf16
  float*          mask = (float*)    (ws + 30146560);        // [256][64]
  unsigned*       sflg = (unsigned*) (ws + 30212096);        // [256]
  unsigned*       bar  = (unsigned*) (ws + 30213120);        // flags[32*32] u32

  k_prep<<<2048, 256, 0, stream>>>(in0,in1,mtok,emb0,emb1,Wihl_f,Whhl_f,Wihh_f,Whhh_f,Wd0_f,Wd1_f,
                                   W0,Wlh,Whhl,Wihh,Whhh,Wd0,Wd1,E,mask,sflg,bar);
  dim3 g1(128,16);
  k_gemm<<<g1, 256, 0, stream>>>(E, W0, bihl, bhhl, xW, nullptr, 2048, 0);
  k_recur<<<NWG, 256, 0, stream>>>(hl0,cl0,hh0,ch0,bihh,bhhh,xW,Whhl,Wlh,Wihh,Whhh,
                                   mask,sflg,hlb,hhb,hseq,bar,dout + 41943040);
  k_gemm<<<g1, 256, 0, stream>>>(hseq, Wd0, bd0, nullptr, nullptr, dout, 2048, 1);
  dim3 g2(128,4);
  k_gemm<<<g2, 256, 0, stream>>>(hseq, Wd1, bd1, nullptr, nullptr, dout + 33554432, 512, 1);
}